// Round 6
// baseline (137.273 us; speedup 1.0000x reference)
//
#include <hip/hip_runtime.h>
#include <hip/hip_bf16.h>

#define NPIX 1801
#define NT   256
#define NB   4096
#define MAXSLICES 32

#define FXSCALE 1048576.0f          // 2^20
#define FXINV   (1.0f / 1048576.0f)
// w = exp(-0.5*(hexdist/sigma)^2) = exp2(-(KHD*m)^2), m = max(|dy|,.866|dx|+.5|dy|)
#define KHD 1.9614249f              // sqrt(0.5*log2(e)) / (inradius*sigma)
#define KHX 1.6986436f              // 0.8660254 * KHD
#define C1  1.4710687f              // 0.75 * KHD  (= KHX*0.8660254)
#define C2  2.9421374f              // 1.5  * KHD  (= KHX*1.7320508)

// Analytic lookup-table inverse (fallback path): pixel index of axial (q,r)
// is col_base(q) + r. Verified rounds 1-5.
__device__ __forceinline__ int col_base(int q) {
    int a = q + 24;
    return (q <= 0) ? (a * 26 + ((a * (a - 1)) >> 1))
                    : (900 + 49 * q - ((q * (q - 1)) >> 1));
}

__device__ __forceinline__ bool in_hex(int q, int r) {
    return (unsigned)(q + 24) <= 48u && (unsigned)(r + 24) <= 48u &&
           (unsigned)(q + r + 24) <= 48u;
}

__device__ __forceinline__ void splat_point(float px, float py, float pv,
                                            unsigned int* hist)
{
    // cartesian -> fractional axial (hex_size == 1, rot == 0, offset == 0)
    float q = fmaf(-0.33333334f, py, 0.57735027f * px);
    float r = 0.66666669f * py;

    // cube round, matching jnp.round (half-to-even)
    float sn = -q - r;
    float qi = rintf(q), ri = rintf(r), si = rintf(sn);
    float dq = fabsf(qi - q), dr = fabsf(ri - r), ds = fabsf(si - sn);
    if (dq > dr && dq > ds)      qi = -ri - si;
    else if (dr > dq && dr > ds) ri = -qi - si;

    int qb = (int)qi;
    int rb = (int)ri;

    float dx = fmaf(-1.7320508f, fmaf(0.5f, ri, qi), px);
    float dy = fmaf(-1.5f, ri, py);

    // K-unit coordinates: all 7 neighbor distances from two scaled values
    float Y  = KHD * dy;
    float X  = KHX * dx;
    float Ym = Y - C2, Yp = Y + C2;
    float Xm = X - C1, Xp = X + C1;
    float XM = X - C2, XP = X + C2;
    float h0 = 0.5f * fabsf(Y);
    float hm = 0.5f * fabsf(Ym);
    float hp = 0.5f * fabsf(Yp);
    // u_n = KHD * hex-metric distance; w_n = exp2(-u_n^2)
    float u0 = fmaxf(fabsf(Y),  fabsf(XP) + h0);   // (-1, 0)
    float u1 = fmaxf(fabsf(Ym), fabsf(Xp) + hm);   // (-1, 1)
    float u2 = fmaxf(fabsf(Yp), fabsf(Xp) + hp);   // ( 0,-1)
    float u3 = fmaxf(fabsf(Y),  fabsf(X)  + h0);   // ( 0, 0)
    float u4 = fmaxf(fabsf(Ym), fabsf(Xm) + hm);   // ( 0, 1)
    float u5 = fmaxf(fabsf(Yp), fabsf(Xm) + hp);   // ( 1,-1)
    float u6 = fmaxf(fabsf(Y),  fabsf(XM) + h0);   // ( 1, 0)
    float w0 = __builtin_amdgcn_exp2f(-(u0 * u0));
    float w1 = __builtin_amdgcn_exp2f(-(u1 * u1));
    float w2 = __builtin_amdgcn_exp2f(-(u2 * u2));
    float w3 = __builtin_amdgcn_exp2f(-(u3 * u3));
    float w4 = __builtin_amdgcn_exp2f(-(u4 * u4));
    float w5 = __builtin_amdgcn_exp2f(-(u5 * u5));
    float w6 = __builtin_amdgcn_exp2f(-(u6 * u6));
    float wsum = ((w0 + w1) + (w2 + w3)) + ((w4 + w5) + w6);
    float vinv = (pv * FXSCALE) * __builtin_amdgcn_rcpf(wsum);

    // interior test in float domain (abs folds to input modifiers)
    bool interior = (fabsf(qi) <= 23.0f) & (fabsf(ri) <= 23.0f) &
                    (fabsf(qi + ri) <= 23.0f);
    if (__builtin_expect(interior, 1)) {
        // closed form: col_base(q) = 900 + sgn(q) * (|q|(99-|q|) >> 1)
        int m  = qb < 0 ? -qb : qb;
        int t  = (m * (99 - m)) >> 1;
        int b1 = 900 + rb + (qb < 0 ? -t : t);
        // column-width deltas: col_base(q)-col_base(q-1) = (99-|2q-1|)>>1
        int t2 = qb + qb;
        int a0 = t2 - 1; a0 = a0 < 0 ? -a0 : a0;
        int a2 = t2 + 1; a2 = a2 < 0 ? -a2 : a2;
        int A0 = b1 - ((99 - a0) >> 1);   // col_base(qb-1)+rb
        int A2 = b1 + ((99 - a2) >> 1);   // col_base(qb+1)+rb
        atomicAdd(&hist[A0],     (unsigned int)(int)(w0 * vinv));
        atomicAdd(&hist[A0 + 1], (unsigned int)(int)(w1 * vinv));
        atomicAdd(&hist[b1 - 1], (unsigned int)(int)(w2 * vinv));
        atomicAdd(&hist[b1],     (unsigned int)(int)(w3 * vinv));
        atomicAdd(&hist[b1 + 1], (unsigned int)(int)(w4 * vinv));
        atomicAdd(&hist[A2 - 1], (unsigned int)(int)(w5 * vinv));
        atomicAdd(&hist[A2],     (unsigned int)(int)(w6 * vinv));
    } else {
        const int nq_[7] = {-1, -1, 0, 0, 0, 1, 1};
        const int nr_[7] = {0, 1, -1, 0, 1, -1, 0};
        float warr[7] = {w0, w1, w2, w3, w4, w5, w6};
        #pragma unroll
        for (int nn = 0; nn < 7; ++nn) {
            int qn = qb + nq_[nn];
            int rn = rb + nr_[nn];
            if (in_hex(qn, rn)) {
                atomicAdd(&hist[col_base(qn) + rn],
                          (unsigned int)(int)(warr[nn] * vinv));
            }
        }
    }
}

__global__ __launch_bounds__(NT) void hexsplat_kernel(
    const float* __restrict__ xs, const float* __restrict__ ys,
    const float* __restrict__ vs, unsigned int* __restrict__ acc,
    int n4, int slice_mask)
{
    __shared__ unsigned int hist[NPIX];
    #pragma unroll 4
    for (int i = threadIdx.x; i < NPIX; i += NT) hist[i] = 0u;
    __syncthreads();

    const int t0 = blockIdx.x * NT + threadIdx.x;
    const float4* x4 = (const float4*)xs;
    const float4* y4 = (const float4*)ys;
    const float4* v4 = (const float4*)vs;

    if (n4 == 2 * NB * NT) {
        // exact-size fast path: issue all 6 loads upfront, then compute
        const int t1 = t0 + NB * NT;
        float4 xa = x4[t0], ya = y4[t0], va = v4[t0];
        float4 xb = x4[t1], yb = y4[t1], vb = v4[t1];
        #pragma unroll
        for (int k = 0; k < 4; ++k)
            splat_point((&xa.x)[k], (&ya.x)[k], (&va.x)[k], hist);
        #pragma unroll
        for (int k = 0; k < 4; ++k)
            splat_point((&xb.x)[k], (&yb.x)[k], (&vb.x)[k], hist);
    } else {
        for (int i = t0; i < n4; i += NB * NT) {
            float4 xq = x4[i], yq = y4[i], vq = v4[i];
            #pragma unroll
            for (int k = 0; k < 4; ++k)
                splat_point((&xq.x)[k], (&yq.x)[k], (&vq.x)[k], hist);
        }
    }

    __syncthreads();
    unsigned int* aslice = acc + (size_t)(blockIdx.x & slice_mask) * NPIX;
    for (int i = threadIdx.x; i < NPIX; i += NT) {
        atomicAdd(&aslice[i], hist[i]);   // exact mod-2^32 merge
    }
}

__global__ void finalize_kernel(const unsigned int* __restrict__ acc,
                                float* __restrict__ out, int nslices)
{
    int i = blockIdx.x * blockDim.x + threadIdx.x;
    if (i < NPIX) {
        unsigned int s = 0;
        for (int k = 0; k < nslices; ++k) s += acc[(size_t)k * NPIX + i];
        out[i] = (float)(int)s * FXINV;
    }
}

extern "C" void kernel_launch(void* const* d_in, const int* in_sizes, int n_in,
                              void* d_out, int out_size, void* d_ws, size_t ws_size,
                              hipStream_t stream) {
    const float* x = (const float*)d_in[0];
    const float* y = (const float*)d_in[1];
    const float* v = (const float*)d_in[2];
    float* out = (float*)d_out;
    unsigned int* acc = (unsigned int*)d_ws;
    int n = in_sizes[0];
    int n4 = n / 4;

    int nslices = 1;
    while (nslices < MAXSLICES &&
           (size_t)(nslices * 2) * NPIX * sizeof(unsigned int) <= ws_size)
        nslices *= 2;

    hipMemsetAsync(acc, 0, (size_t)nslices * NPIX * sizeof(unsigned int), stream);
    hexsplat_kernel<<<NB, NT, 0, stream>>>(x, y, v, acc, n4, nslices - 1);
    finalize_kernel<<<(NPIX + 255) / 256, 256, 0, stream>>>(acc, out, nslices);
}

// Round 7
// 137.124 us; speedup vs baseline: 1.0011x; 1.0011x over previous
//
#include <hip/hip_runtime.h>
#include <hip/hip_bf16.h>

#define NPIX 1801
#define NT   256
#define NB   4096
#define MAXSLICES 32

#define FXSCALE 1048576.0f          // 2^20
#define FXINV   (1.0f / 1048576.0f)
// w = exp(-0.5*(hexdist/sigma)^2) = exp2(-(KHD*m)^2), m = max(|dy|,.866|dx|+.5|dy|)
#define KHD 1.9614249f              // sqrt(2*log2(e)) / inradius  (sigma=0.5 folded)
#define KHX 1.6986436f              // 0.8660254 * KHD
#define C1  1.4710687f              // 0.75 * KHD
#define C2  2.9421374f              // 1.5  * KHD

typedef float v2f __attribute__((ext_vector_type(2)));

__device__ __forceinline__ v2f v2abs(v2f a) { return __builtin_elementwise_abs(a); }
__device__ __forceinline__ v2f v2max(v2f a, v2f b) { return __builtin_elementwise_max(a, b); }

// Analytic lookup-table inverse (fallback path): pixel index of axial (q,r)
// is col_base(q) + r. Verified rounds 1-6.
__device__ __forceinline__ int col_base(int q) {
    int a = q + 24;
    return (q <= 0) ? (a * 26 + ((a * (a - 1)) >> 1))
                    : (900 + 49 * q - ((q * (q - 1)) >> 1));
}

__device__ __forceinline__ bool in_hex(int q, int r) {
    return (unsigned)(q + 24) <= 48u && (unsigned)(r + 24) <= 48u &&
           (unsigned)(q + r + 24) <= 48u;
}

__device__ __forceinline__ void splat_point(float px, float py, float pv,
                                            unsigned int* hist)
{
    // cartesian -> fractional axial (hex_size == 1, rot == 0, offset == 0)
    float q = fmaf(-0.33333334f, py, 0.57735027f * px);
    float r = 0.66666669f * py;

    // cube round, matching jnp.round (half-to-even)
    float sn = -q - r;
    float qi = rintf(q), ri = rintf(r), si = rintf(sn);
    float dq = fabsf(qi - q), dr = fabsf(ri - r), ds = fabsf(si - sn);
    if (dq > dr && dq > ds)      qi = -ri - si;
    else if (dr > dq && dr > ds) ri = -qi - si;

    int qb = (int)qi;
    int rb = (int)ri;

    float dx = fmaf(-1.7320508f, fmaf(0.5f, ri, qi), px);
    float dy = fmaf(-1.5f, ri, py);

    // K-unit coordinates; packed fp32 (v_pk_*) over the ±C symmetric pairs
    float Y  = KHD * dy;
    float X  = KHX * dx;
    float aY = fabsf(Y);
    float aX = fabsf(X);
    float h0 = 0.5f * aY;

    v2f Ymp  = (v2f){Y, Y} + (v2f){-C2, C2};    // {Ym, Yp}
    v2f Xmp  = (v2f){X, X} + (v2f){-C1, C1};    // {Xm, Xp}
    v2f XPM  = (v2f){X, X} + (v2f){C2, -C2};    // {XP, XM}
    v2f aYmp = v2abs(Ymp);
    v2f aXmp = v2abs(Xmp);
    v2f aXPM = v2abs(XPM);
    v2f hmp  = (v2f){0.5f, 0.5f} * aYmp;        // {hm, hp}

    // u1=(-1,1): max(|Ym|,|Xp|+hm)  u2=(0,-1): max(|Yp|,|Xp|+hp)
    v2f u12 = v2max(aYmp, (v2f){aXmp.y, aXmp.y} + hmp);
    // u4=(0,1):  max(|Ym|,|Xm|+hm)  u5=(1,-1): max(|Yp|,|Xm|+hp)
    v2f u45 = v2max(aYmp, (v2f){aXmp.x, aXmp.x} + hmp);
    // u0=(-1,0): max(|Y|,|XP|+h0)   u6=(1,0):  max(|Y|,|XM|+h0)
    v2f u06 = v2max((v2f){aY, aY}, aXPM + (v2f){h0, h0});
    float u3 = fmaxf(aY, aX + h0);              // (0,0)

    v2f s12 = u12 * u12;
    v2f s45 = u45 * u45;
    v2f s06 = u06 * u06;
    float s3 = u3 * u3;

    float w0 = __builtin_amdgcn_exp2f(-s06.x);
    float w1 = __builtin_amdgcn_exp2f(-s12.x);
    float w2 = __builtin_amdgcn_exp2f(-s12.y);
    float w3 = __builtin_amdgcn_exp2f(-s3);
    float w4 = __builtin_amdgcn_exp2f(-s45.x);
    float w5 = __builtin_amdgcn_exp2f(-s45.y);
    float w6 = __builtin_amdgcn_exp2f(-s06.y);
    float wsum = ((w0 + w1) + (w2 + w3)) + ((w4 + w5) + w6);
    float vinv = (pv * FXSCALE) * __builtin_amdgcn_rcpf(wsum);

    // interior test (always true for this input box; else-path is insurance)
    float mi = fmaxf(fmaxf(fabsf(qi), fabsf(ri)), fabsf(qi + ri));
    if (__builtin_expect(mi <= 23.0f, 1)) {
        // closed form: col_base(q) = 900 + sgn(q) * (|q|(99-|q|) >> 1)
        int m  = qb < 0 ? -qb : qb;
        int t  = (m * (99 - m)) >> 1;
        int b1 = 900 + rb + (qb < 0 ? -t : t);
        // column-width deltas: col_base(q)-col_base(q-1) = (99-|2q-1|)>>1
        int t2 = qb + qb;
        int a0 = t2 - 1; a0 = a0 < 0 ? -a0 : a0;
        int a2 = t2 + 1; a2 = a2 < 0 ? -a2 : a2;
        int A0 = b1 - ((99 - a0) >> 1);   // col_base(qb-1)+rb
        int A2 = b1 + ((99 - a2) >> 1);   // col_base(qb+1)+rb
        atomicAdd(&hist[A0],     (unsigned int)(int)(w0 * vinv));
        atomicAdd(&hist[A0 + 1], (unsigned int)(int)(w1 * vinv));
        atomicAdd(&hist[b1 - 1], (unsigned int)(int)(w2 * vinv));
        atomicAdd(&hist[b1],     (unsigned int)(int)(w3 * vinv));
        atomicAdd(&hist[b1 + 1], (unsigned int)(int)(w4 * vinv));
        atomicAdd(&hist[A2 - 1], (unsigned int)(int)(w5 * vinv));
        atomicAdd(&hist[A2],     (unsigned int)(int)(w6 * vinv));
    } else {
        const int nq_[7] = {-1, -1, 0, 0, 0, 1, 1};
        const int nr_[7] = {0, 1, -1, 0, 1, -1, 0};
        float warr[7] = {w0, w1, w2, w3, w4, w5, w6};
        #pragma unroll
        for (int nn = 0; nn < 7; ++nn) {
            int qn = qb + nq_[nn];
            int rn = rb + nr_[nn];
            if (in_hex(qn, rn)) {
                atomicAdd(&hist[col_base(qn) + rn],
                          (unsigned int)(int)(warr[nn] * vinv));
            }
        }
    }
}

__global__ __launch_bounds__(NT) void hexsplat_kernel(
    const float* __restrict__ xs, const float* __restrict__ ys,
    const float* __restrict__ vs, unsigned int* __restrict__ acc,
    int n4, int slice_mask)
{
    const int t0 = blockIdx.x * NT + threadIdx.x;
    const float4* x4 = (const float4*)xs;
    const float4* y4 = (const float4*)ys;
    const float4* v4 = (const float4*)vs;

    // hoist iteration-0 loads above LDS init so HBM latency hides under it
    float4 xa, ya, va;
    bool have0 = t0 < n4;
    if (have0) { xa = x4[t0]; ya = y4[t0]; va = v4[t0]; }

    __shared__ unsigned int hist[NPIX];
    #pragma unroll 4
    for (int i = threadIdx.x; i < NPIX; i += NT) hist[i] = 0u;
    __syncthreads();

    if (have0) {
        #pragma unroll
        for (int k = 0; k < 4; ++k)
            splat_point((&xa.x)[k], (&ya.x)[k], (&va.x)[k], hist);
    }
    for (int i = t0 + NB * NT; i < n4; i += NB * NT) {
        float4 xq = x4[i], yq = y4[i], vq = v4[i];
        #pragma unroll
        for (int k = 0; k < 4; ++k)
            splat_point((&xq.x)[k], (&yq.x)[k], (&vq.x)[k], hist);
    }

    __syncthreads();
    unsigned int* aslice = acc + (size_t)(blockIdx.x & slice_mask) * NPIX;
    for (int i = threadIdx.x; i < NPIX; i += NT) {
        atomicAdd(&aslice[i], hist[i]);   // exact mod-2^32 merge
    }
}

__global__ void finalize_kernel(const unsigned int* __restrict__ acc,
                                float* __restrict__ out, int nslices)
{
    int i = blockIdx.x * blockDim.x + threadIdx.x;
    if (i < NPIX) {
        unsigned int s = 0;
        for (int k = 0; k < nslices; ++k) s += acc[(size_t)k * NPIX + i];
        out[i] = (float)(int)s * FXINV;
    }
}

extern "C" void kernel_launch(void* const* d_in, const int* in_sizes, int n_in,
                              void* d_out, int out_size, void* d_ws, size_t ws_size,
                              hipStream_t stream) {
    const float* x = (const float*)d_in[0];
    const float* y = (const float*)d_in[1];
    const float* v = (const float*)d_in[2];
    float* out = (float*)d_out;
    unsigned int* acc = (unsigned int*)d_ws;
    int n = in_sizes[0];
    int n4 = n / 4;

    int nslices = 1;
    while (nslices < MAXSLICES &&
           (size_t)(nslices * 2) * NPIX * sizeof(unsigned int) <= ws_size)
        nslices *= 2;

    hipMemsetAsync(acc, 0, (size_t)nslices * NPIX * sizeof(unsigned int), stream);
    hexsplat_kernel<<<NB, NT, 0, stream>>>(x, y, v, acc, n4, nslices - 1);
    finalize_kernel<<<(NPIX + 255) / 256, 256, 0, stream>>>(acc, out, nslices);
}

// Round 8
// 132.180 us; speedup vs baseline: 1.0385x; 1.0374x over previous
//
#include <hip/hip_runtime.h>
#include <hip/hip_bf16.h>

#define NPIX 1801
#define NT   256
#define NB   2048
#define MAXSLICES 32

#define FXSCALE 1048576.0f          // 2^20
#define FXINV   (1.0f / 1048576.0f)
// w = exp(-0.5*(hexdist/sigma)^2) = exp2(-(KHD*m)^2), m = max(|dy|,.866|dx|+.5|dy|)
#define KHD 1.9614249f              // sqrt(2*log2(e)) / inradius  (sigma=0.5 folded)
#define KHX 1.6986436f              // 0.8660254 * KHD
#define C1  1.4710687f              // 0.75 * KHD
#define C2  2.9421374f              // 1.5  * KHD

// Analytic lookup-table inverse (fallback path): pixel index of axial (q,r)
// is col_base(q) + r. Verified rounds 1-7.
__device__ __forceinline__ int col_base(int q) {
    int a = q + 24;
    return (q <= 0) ? (a * 26 + ((a * (a - 1)) >> 1))
                    : (900 + 49 * q - ((q * (q - 1)) >> 1));
}

__device__ __forceinline__ bool in_hex(int q, int r) {
    return (unsigned)(q + 24) <= 48u && (unsigned)(r + 24) <= 48u &&
           (unsigned)(q + r + 24) <= 48u;
}

__device__ __forceinline__ void splat_point(float px, float py, float pv,
                                            unsigned int* hist)
{
    // cartesian -> fractional axial (hex_size == 1, rot == 0, offset == 0)
    float q = fmaf(-0.33333334f, py, 0.57735027f * px);
    float r = 0.66666669f * py;

    // cube round, matching jnp.round (half-to-even)
    float sn = -q - r;
    float qi = rintf(q), ri = rintf(r), si = rintf(sn);
    float dq = fabsf(qi - q), dr = fabsf(ri - r), ds = fabsf(si - sn);
    if (dq > dr && dq > ds)      qi = -ri - si;
    else if (dr > dq && dr > ds) ri = -qi - si;

    int qb = (int)qi;
    int rb = (int)ri;

    float dx = fmaf(-1.7320508f, fmaf(0.5f, ri, qi), px);
    float dy = fmaf(-1.5f, ri, py);

    // K-unit coordinates: all 7 neighbor distances from two scaled values
    float Y  = KHD * dy;
    float X  = KHX * dx;
    float Ym = Y - C2, Yp = Y + C2;
    float Xm = X - C1, Xp = X + C1;
    float XM = X - C2, XP = X + C2;
    float h0 = 0.5f * fabsf(Y);
    float hm = 0.5f * fabsf(Ym);
    float hp = 0.5f * fabsf(Yp);
    // u_n = KHD * hex-metric distance; w_n = exp2(-u_n^2)
    float u0 = fmaxf(fabsf(Y),  fabsf(XP) + h0);   // (-1, 0)
    float u1 = fmaxf(fabsf(Ym), fabsf(Xp) + hm);   // (-1, 1)
    float u2 = fmaxf(fabsf(Yp), fabsf(Xp) + hp);   // ( 0,-1)
    float u3 = fmaxf(fabsf(Y),  fabsf(X)  + h0);   // ( 0, 0)
    float u4 = fmaxf(fabsf(Ym), fabsf(Xm) + hm);   // ( 0, 1)
    float u5 = fmaxf(fabsf(Yp), fabsf(Xm) + hp);   // ( 1,-1)
    float u6 = fmaxf(fabsf(Y),  fabsf(XM) + h0);   // ( 1, 0)
    float w0 = __builtin_amdgcn_exp2f(-(u0 * u0));
    float w1 = __builtin_amdgcn_exp2f(-(u1 * u1));
    float w2 = __builtin_amdgcn_exp2f(-(u2 * u2));
    float w3 = __builtin_amdgcn_exp2f(-(u3 * u3));
    float w4 = __builtin_amdgcn_exp2f(-(u4 * u4));
    float w5 = __builtin_amdgcn_exp2f(-(u5 * u5));
    float w6 = __builtin_amdgcn_exp2f(-(u6 * u6));
    float wsum = ((w0 + w1) + (w2 + w3)) + ((w4 + w5) + w6);
    float vinv = (pv * FXSCALE) * __builtin_amdgcn_rcpf(wsum);

    // interior test (always true for this input box; else-path is insurance)
    bool interior = (fabsf(qi) <= 23.0f) & (fabsf(ri) <= 23.0f) &
                    (fabsf(qi + ri) <= 23.0f);
    if (__builtin_expect(interior, 1)) {
        // closed form: col_base(q) = 900 + sgn(q) * (|q|(99-|q|) >> 1)
        int m  = qb < 0 ? -qb : qb;
        int t  = (m * (99 - m)) >> 1;
        int b1 = 900 + rb + (qb < 0 ? -t : t);
        // column-width deltas: col_base(q)-col_base(q-1) = (99-|2q-1|)>>1
        int t2 = qb + qb;
        int a0 = t2 - 1; a0 = a0 < 0 ? -a0 : a0;
        int a2 = t2 + 1; a2 = a2 < 0 ? -a2 : a2;
        int A0 = b1 - ((99 - a0) >> 1);   // col_base(qb-1)+rb
        int A2 = b1 + ((99 - a2) >> 1);   // col_base(qb+1)+rb
        atomicAdd(&hist[A0],     (unsigned int)(int)(w0 * vinv));
        atomicAdd(&hist[A0 + 1], (unsigned int)(int)(w1 * vinv));
        atomicAdd(&hist[b1 - 1], (unsigned int)(int)(w2 * vinv));
        atomicAdd(&hist[b1],     (unsigned int)(int)(w3 * vinv));
        atomicAdd(&hist[b1 + 1], (unsigned int)(int)(w4 * vinv));
        atomicAdd(&hist[A2 - 1], (unsigned int)(int)(w5 * vinv));
        atomicAdd(&hist[A2],     (unsigned int)(int)(w6 * vinv));
    } else {
        const int nq_[7] = {-1, -1, 0, 0, 0, 1, 1};
        const int nr_[7] = {0, 1, -1, 0, 1, -1, 0};
        float warr[7] = {w0, w1, w2, w3, w4, w5, w6};
        #pragma unroll
        for (int nn = 0; nn < 7; ++nn) {
            int qn = qb + nq_[nn];
            int rn = rb + nr_[nn];
            if (in_hex(qn, rn)) {
                atomicAdd(&hist[col_base(qn) + rn],
                          (unsigned int)(int)(warr[nn] * vinv));
            }
        }
    }
}

__global__ __launch_bounds__(NT) void hexsplat_kernel(
    const float* __restrict__ xs, const float* __restrict__ ys,
    const float* __restrict__ vs, unsigned int* __restrict__ acc,
    int n4, int slice_mask)
{
    const int t0 = blockIdx.x * NT + threadIdx.x;
    const int stride = NB * NT;
    const float4* x4 = (const float4*)xs;
    const float4* y4 = (const float4*)ys;
    const float4* v4 = (const float4*)vs;

    __shared__ unsigned int hist[NPIX];
    #pragma unroll 4
    for (int i = threadIdx.x; i < NPIX; i += NT) hist[i] = 0u;

    // single-generation grid (8 blocks/CU resident): 4 iterations/thread,
    // 1-ahead prefetch so next loads are in flight during current compute
    float4 xc, yc, vc;
    bool havec = t0 < n4;
    if (havec) { xc = x4[t0]; yc = y4[t0]; vc = v4[t0]; }
    __syncthreads();

    for (int i = t0; i < n4; i += stride) {
        float4 xn, yn, vn;
        int inext = i + stride;
        bool haven = inext < n4;
        if (haven) { xn = x4[inext]; yn = y4[inext]; vn = v4[inext]; }
        #pragma unroll
        for (int k = 0; k < 4; ++k)
            splat_point((&xc.x)[k], (&yc.x)[k], (&vc.x)[k], hist);
        xc = xn; yc = yn; vc = vn;
    }

    __syncthreads();
    unsigned int* aslice = acc + (size_t)(blockIdx.x & slice_mask) * NPIX;
    for (int i = threadIdx.x; i < NPIX; i += NT) {
        atomicAdd(&aslice[i], hist[i]);   // exact mod-2^32 merge
    }
}

__global__ void finalize_kernel(const unsigned int* __restrict__ acc,
                                float* __restrict__ out, int nslices)
{
    int i = blockIdx.x * blockDim.x + threadIdx.x;
    if (i < NPIX) {
        unsigned int s = 0;
        for (int k = 0; k < nslices; ++k) s += acc[(size_t)k * NPIX + i];
        out[i] = (float)(int)s * FXINV;
    }
}

extern "C" void kernel_launch(void* const* d_in, const int* in_sizes, int n_in,
                              void* d_out, int out_size, void* d_ws, size_t ws_size,
                              hipStream_t stream) {
    const float* x = (const float*)d_in[0];
    const float* y = (const float*)d_in[1];
    const float* v = (const float*)d_in[2];
    float* out = (float*)d_out;
    unsigned int* acc = (unsigned int*)d_ws;
    int n = in_sizes[0];
    int n4 = n / 4;

    int nslices = 1;
    while (nslices < MAXSLICES &&
           (size_t)(nslices * 2) * NPIX * sizeof(unsigned int) <= ws_size)
        nslices *= 2;

    hipMemsetAsync(acc, 0, (size_t)nslices * NPIX * sizeof(unsigned int), stream);
    hexsplat_kernel<<<NB, NT, 0, stream>>>(x, y, v, acc, n4, nslices - 1);
    finalize_kernel<<<(NPIX + 255) / 256, 256, 0, stream>>>(acc, out, nslices);
}